// Round 1
// baseline (1722.002 us; speedup 1.0000x reference)
//
#include <hip/hip_runtime.h>

#define N_NODES 100000
#define F_IN 128
#define F_H 64
#define F_OUT 16

// ---------------------------------------------------------------------------
// GEMM1: h1[N,64] = x[N,128] @ W1[128,64]
// Block: 256 threads, tile 64 nodes x 64 feats, K tiled in 2 phases of 64.
// Thread tile: 4 nodes x 4 feats. LDS: W tile 16KB + X tile 17.6KB.
// ---------------------------------------------------------------------------
__global__ __launch_bounds__(256) void gemm1_kernel(
    const float* __restrict__ x, const float* __restrict__ W,
    float* __restrict__ h1, int N) {
    __shared__ float Wlds[64 * 64];      // [kk][f]
    __shared__ float Xlds[64][69];       // [node][kk], pad 69 -> 2-way max (free)

    const int tid = threadIdx.x;
    const int n0 = blockIdx.x * 64;
    const int tf = tid & 15;             // feat quad: feats 4*tf..4*tf+3 (lane-fast -> coalesced C store)
    const int tn = tid >> 4;             // node quad: nodes 4*tn..4*tn+3

    float acc[4][4] = {{0.f, 0.f, 0.f, 0.f}, {0.f, 0.f, 0.f, 0.f},
                       {0.f, 0.f, 0.f, 0.f}, {0.f, 0.f, 0.f, 0.f}};

    for (int p = 0; p < 2; ++p) {
        // load W tile [64k x 64f]: 1024 float4
        for (int i = tid; i < 1024; i += 256) {
            const int kk = i >> 4, c4 = i & 15;
            float4 v = *(const float4*)(W + (size_t)(64 * p + kk) * 64 + 4 * c4);
            *(float4*)(&Wlds[kk * 64 + 4 * c4]) = v;
        }
        // load X tile [64n x 64k] (clamp OOB rows; stores guarded later)
        for (int i = tid; i < 1024; i += 256) {
            const int row = i >> 4, c4 = i & 15;
            int n = n0 + row;
            if (n >= N) n = N - 1;
            float4 v = *(const float4*)(x + (size_t)n * F_IN + 64 * p + 4 * c4);
            Xlds[row][4 * c4 + 0] = v.x;
            Xlds[row][4 * c4 + 1] = v.y;
            Xlds[row][4 * c4 + 2] = v.z;
            Xlds[row][4 * c4 + 3] = v.w;
        }
        __syncthreads();

        #pragma unroll 4
        for (int kk = 0; kk < 64; ++kk) {
            float4 w4 = *(const float4*)(&Wlds[kk * 64 + 4 * tf]);
            float xv[4];
            #pragma unroll
            for (int i2 = 0; i2 < 4; ++i2) xv[i2] = Xlds[4 * tn + i2][kk];
            #pragma unroll
            for (int i2 = 0; i2 < 4; ++i2) {
                acc[i2][0] += xv[i2] * w4.x;
                acc[i2][1] += xv[i2] * w4.y;
                acc[i2][2] += xv[i2] * w4.z;
                acc[i2][3] += xv[i2] * w4.w;
            }
        }
        __syncthreads();
    }

    #pragma unroll
    for (int i2 = 0; i2 < 4; ++i2) {
        const int n = n0 + 4 * tn + i2;
        if (n < N) {
            float4 o = make_float4(acc[i2][0], acc[i2][1], acc[i2][2], acc[i2][3]);
            *(float4*)(h1 + (size_t)n * F_H + 4 * tf) = o;
        }
    }
}

// ---------------------------------------------------------------------------
// init agg buffer to broadcast bias (the "+ b" of each GraphConv)
// total4 = N*F/4 float4 stores; fmask = F/4 - 1 (power of 2)
// ---------------------------------------------------------------------------
__global__ __launch_bounds__(256) void init_bias_kernel(
    float* __restrict__ dst, const float* __restrict__ b, int total4, int fmask) {
    const int i = blockIdx.x * 256 + threadIdx.x;
    if (i >= total4) return;
    float4 bv = ((const float4*)b)[i & fmask];
    ((float4*)dst)[i] = bv;
}

// ---------------------------------------------------------------------------
// scatter1: agg1[dst] += h1[src] * ew   (64 feats, 16 threads/edge)
// ---------------------------------------------------------------------------
__global__ __launch_bounds__(256) void scatter1_kernel(
    const float* __restrict__ h1, const int* __restrict__ src,
    const int* __restrict__ dst, const float* __restrict__ ew,
    float* __restrict__ agg, int E) {
    const int gid = blockIdx.x * 256 + threadIdx.x;
    const int e = gid >> 4;
    if (e >= E) return;
    const int f4 = gid & 15;
    const int s = src[e];
    const int d = dst[e];
    const float w = ew[e];
    float4 v = *(const float4*)(h1 + (size_t)s * F_H + 4 * f4);
    float* p = agg + (size_t)d * F_H + 4 * f4;
    atomicAdd(p + 0, v.x * w);
    atomicAdd(p + 1, v.y * w);
    atomicAdd(p + 2, v.z * w);
    atomicAdd(p + 3, v.w * w);
}

// ---------------------------------------------------------------------------
// GEMM2: h2[N,16] = relu(agg1[N,64]) @ W2[64,16]   (relu fused into LDS load)
// Block: 256 threads, 64 nodes. Thread: 1 node x 4 feats.
// ---------------------------------------------------------------------------
__global__ __launch_bounds__(256) void gemm2_kernel(
    const float* __restrict__ agg1, const float* __restrict__ W2,
    float* __restrict__ h2, int N) {
    __shared__ float Wlds[64 * 16];      // 4KB
    __shared__ float Xlds[64][65];       // 16.6KB, pad 65 -> conflict-free reads

    const int tid = threadIdx.x;
    const int n0 = blockIdx.x * 64;

    {   // load W2 (1024 floats = 256 float4, one per thread)
        float4 v = ((const float4*)W2)[tid];
        ((float4*)Wlds)[tid] = v;
    }
    for (int i = tid; i < 64 * 16; i += 256) {
        const int row = i >> 4, c4 = i & 15;
        int n = n0 + row;
        if (n >= N) n = N - 1;
        float4 v = *(const float4*)(agg1 + (size_t)n * F_H + 4 * c4);
        Xlds[row][4 * c4 + 0] = fmaxf(v.x, 0.f);
        Xlds[row][4 * c4 + 1] = fmaxf(v.y, 0.f);
        Xlds[row][4 * c4 + 2] = fmaxf(v.z, 0.f);
        Xlds[row][4 * c4 + 3] = fmaxf(v.w, 0.f);
    }
    __syncthreads();

    const int tf4 = tid & 3;             // feat quad (lane-fast with tn -> coalesced store)
    const int tn = tid >> 2;             // node 0..63
    float a0 = 0.f, a1 = 0.f, a2 = 0.f, a3 = 0.f;
    #pragma unroll 8
    for (int k = 0; k < 64; ++k) {
        const float xv = Xlds[tn][k];
        float4 w4 = *(const float4*)(&Wlds[k * 16 + 4 * tf4]);
        a0 += xv * w4.x;
        a1 += xv * w4.y;
        a2 += xv * w4.z;
        a3 += xv * w4.w;
    }
    const int n = n0 + tn;
    if (n < N) {
        *(float4*)(h2 + (size_t)n * F_OUT + 4 * tf4) = make_float4(a0, a1, a2, a3);
    }
}

// ---------------------------------------------------------------------------
// scatter2: out[dst] += h2[src] * ew   (16 feats, 4 threads/edge)
// ---------------------------------------------------------------------------
__global__ __launch_bounds__(256) void scatter2_kernel(
    const float* __restrict__ h2, const int* __restrict__ src,
    const int* __restrict__ dst, const float* __restrict__ ew,
    float* __restrict__ out, int E) {
    const int gid = blockIdx.x * 256 + threadIdx.x;
    const int e = gid >> 2;
    if (e >= E) return;
    const int f4 = gid & 3;
    const int s = src[e];
    const int d = dst[e];
    const float w = ew[e];
    float4 v = *(const float4*)(h2 + (size_t)s * F_OUT + 4 * f4);
    float* p = out + (size_t)d * F_OUT + 4 * f4;
    atomicAdd(p + 0, v.x * w);
    atomicAdd(p + 1, v.y * w);
    atomicAdd(p + 2, v.z * w);
    atomicAdd(p + 3, v.w * w);
}

extern "C" void kernel_launch(void* const* d_in, const int* in_sizes, int n_in,
                              void* d_out, int out_size, void* d_ws, size_t ws_size,
                              hipStream_t stream) {
    const float* x   = (const float*)d_in[0];
    const int*   src = (const int*)d_in[1];
    const int*   dst = (const int*)d_in[2];
    const float* ew  = (const float*)d_in[3];
    const float* W1  = (const float*)d_in[4];
    const float* b1  = (const float*)d_in[5];
    const float* W2  = (const float*)d_in[6];
    const float* b2  = (const float*)d_in[7];
    float* out = (float*)d_out;

    const int N = in_sizes[0] / F_IN;    // 100000
    const int E = in_sizes[1];           // 1600000

    float* h1   = (float*)d_ws;                       // N*64 floats (25.6 MB)
    float* agg1 = h1 + (size_t)N * F_H;               // N*64 floats (25.6 MB)
    float* h2   = h1;                                 // reuse h1's region (N*16)

    // layer 1
    gemm1_kernel<<<(N + 63) / 64, 256, 0, stream>>>(x, W1, h1, N);
    init_bias_kernel<<<(N * (F_H / 4) + 255) / 256, 256, 0, stream>>>(
        agg1, b1, N * (F_H / 4), F_H / 4 - 1);
    scatter1_kernel<<<((long long)E * 16 + 255) / 256, 256, 0, stream>>>(
        h1, src, dst, ew, agg1, E);

    // layer 2 (relu fused into gemm2 load)
    gemm2_kernel<<<(N + 63) / 64, 256, 0, stream>>>(agg1, W2, h2, N);
    init_bias_kernel<<<(N * (F_OUT / 4) + 255) / 256, 256, 0, stream>>>(
        out, b2, N * (F_OUT / 4), F_OUT / 4 - 1);
    scatter2_kernel<<<((long long)E * 4 + 255) / 256, 256, 0, stream>>>(
        h2, src, dst, ew, out, E);
}

// Round 2
// 330.308 us; speedup vs baseline: 5.2133x; 5.2133x over previous
//
#include <hip/hip_runtime.h>

#define F_IN 128
#define F_H 64
#define F_OUT 16

typedef unsigned long long u64;
typedef unsigned int u32;

// ---------------------------------------------------------------------------
// GEMM1: h1[N,64] = x[N,128] @ W1[128,64]  (unchanged from R1)
// ---------------------------------------------------------------------------
__global__ __launch_bounds__(256) void gemm1_kernel(
    const float* __restrict__ x, const float* __restrict__ W,
    float* __restrict__ h1, int N) {
    __shared__ float Wlds[64 * 64];
    __shared__ float Xlds[64][69];

    const int tid = threadIdx.x;
    const int n0 = blockIdx.x * 64;
    const int tf = tid & 15;
    const int tn = tid >> 4;

    float acc[4][4] = {{0.f, 0.f, 0.f, 0.f}, {0.f, 0.f, 0.f, 0.f},
                       {0.f, 0.f, 0.f, 0.f}, {0.f, 0.f, 0.f, 0.f}};

    for (int p = 0; p < 2; ++p) {
        for (int i = tid; i < 1024; i += 256) {
            const int kk = i >> 4, c4 = i & 15;
            float4 v = *(const float4*)(W + (size_t)(64 * p + kk) * 64 + 4 * c4);
            *(float4*)(&Wlds[kk * 64 + 4 * c4]) = v;
        }
        for (int i = tid; i < 1024; i += 256) {
            const int row = i >> 4, c4 = i & 15;
            int n = n0 + row;
            if (n >= N) n = N - 1;
            float4 v = *(const float4*)(x + (size_t)n * F_IN + 64 * p + 4 * c4);
            Xlds[row][4 * c4 + 0] = v.x;
            Xlds[row][4 * c4 + 1] = v.y;
            Xlds[row][4 * c4 + 2] = v.z;
            Xlds[row][4 * c4 + 3] = v.w;
        }
        __syncthreads();

        #pragma unroll 4
        for (int kk = 0; kk < 64; ++kk) {
            float4 w4 = *(const float4*)(&Wlds[kk * 64 + 4 * tf]);
            float xv[4];
            #pragma unroll
            for (int i2 = 0; i2 < 4; ++i2) xv[i2] = Xlds[4 * tn + i2][kk];
            #pragma unroll
            for (int i2 = 0; i2 < 4; ++i2) {
                acc[i2][0] += xv[i2] * w4.x;
                acc[i2][1] += xv[i2] * w4.y;
                acc[i2][2] += xv[i2] * w4.z;
                acc[i2][3] += xv[i2] * w4.w;
            }
        }
        __syncthreads();
    }

    #pragma unroll
    for (int i2 = 0; i2 < 4; ++i2) {
        const int n = n0 + 4 * tn + i2;
        if (n < N) {
            float4 o = make_float4(acc[i2][0], acc[i2][1], acc[i2][2], acc[i2][3]);
            *(float4*)(h1 + (size_t)n * F_H + 4 * tf) = o;
        }
    }
}

// ---------------------------------------------------------------------------
// CSR build: histogram -> 2-level exclusive scan -> fill packed {w,src}
// deg[] doubles as the fill cursor after the scan copies rowptr into it.
// ---------------------------------------------------------------------------
__global__ __launch_bounds__(256) void hist_kernel(
    const int* __restrict__ dst, int* __restrict__ deg, int E) {
    const int e = blockIdx.x * 256 + threadIdx.x;
    if (e < E) atomicAdd(&deg[dst[e]], 1);
}

__global__ __launch_bounds__(256) void partial_kernel(
    const int* __restrict__ deg, int* __restrict__ part, int N) {
    __shared__ int s[256];
    const int gid = blockIdx.x * 256 + threadIdx.x;
    s[threadIdx.x] = (gid < N) ? deg[gid] : 0;
    __syncthreads();
    for (int o = 128; o > 0; o >>= 1) {
        if (threadIdx.x < o) s[threadIdx.x] += s[threadIdx.x + o];
        __syncthreads();
    }
    if (threadIdx.x == 0) part[blockIdx.x] = s[0];
}

__global__ __launch_bounds__(512) void scanpart_kernel(int* __restrict__ part, int NB) {
    __shared__ int s[512];
    const int t = threadIdx.x;
    const int v = (t < NB) ? part[t] : 0;
    s[t] = v;
    __syncthreads();
    for (int o = 1; o < 512; o <<= 1) {
        int a = (t >= o) ? s[t - o] : 0;
        __syncthreads();
        s[t] += a;
        __syncthreads();
    }
    if (t < NB) part[t] = s[t] - v;  // exclusive
}

__global__ __launch_bounds__(256) void scanfinal_kernel(
    int* __restrict__ deg, const int* __restrict__ part,
    int* __restrict__ rowptr, int N, int E) {
    __shared__ int s[256];
    const int t = threadIdx.x;
    const int gid = blockIdx.x * 256 + t;
    const int v = (gid < N) ? deg[gid] : 0;
    s[t] = v;
    __syncthreads();
    for (int o = 1; o < 256; o <<= 1) {
        int a = (t >= o) ? s[t - o] : 0;
        __syncthreads();
        s[t] += a;
        __syncthreads();
    }
    const int val = part[blockIdx.x] + s[t] - v;  // exclusive prefix of deg
    if (gid < N) {
        rowptr[gid] = val;
        deg[gid] = val;     // becomes the fill cursor
    }
    if (gid == N) rowptr[N] = E;
}

__global__ __launch_bounds__(256) void fill_kernel(
    const int* __restrict__ src, const int* __restrict__ dst,
    const float* __restrict__ ew, int* __restrict__ cursor,
    u64* __restrict__ edata, int E) {
    const int e = blockIdx.x * 256 + threadIdx.x;
    if (e >= E) return;
    const int d = dst[e];
    const int pos = atomicAdd(&cursor[d], 1);
    const u64 packed = ((u64)__float_as_uint(ew[e]) << 32) | (u32)src[e];
    edata[pos] = packed;
}

// ---------------------------------------------------------------------------
// agg64: agg[n] = b + sum_{e in CSR[n]} w_e * h[src_e]   (F=64, 16 lanes/node)
// ---------------------------------------------------------------------------
__global__ __launch_bounds__(256) void agg64_kernel(
    const float* __restrict__ h, const u64* __restrict__ edata,
    const int* __restrict__ rowptr, const float* __restrict__ bias,
    float* __restrict__ agg, int N) {
    const int tid = threadIdx.x;
    const int n = blockIdx.x * 16 + (tid >> 4);
    const int f4 = tid & 15;
    if (n >= N) return;

    float4 acc = *(const float4*)(bias + 4 * f4);
    int i = rowptr[n];
    const int end = rowptr[n + 1];

    for (; i + 1 < end; i += 2) {   // unroll-2: two independent gathers in flight
        const u64 e0 = edata[i], e1 = edata[i + 1];
        const int s0 = (int)(u32)e0, s1 = (int)(u32)e1;
        const float w0 = __uint_as_float((u32)(e0 >> 32));
        const float w1 = __uint_as_float((u32)(e1 >> 32));
        const float4 v0 = *(const float4*)(h + (size_t)s0 * F_H + 4 * f4);
        const float4 v1 = *(const float4*)(h + (size_t)s1 * F_H + 4 * f4);
        acc.x += v0.x * w0 + v1.x * w1;
        acc.y += v0.y * w0 + v1.y * w1;
        acc.z += v0.z * w0 + v1.z * w1;
        acc.w += v0.w * w0 + v1.w * w1;
    }
    if (i < end) {
        const u64 e0 = edata[i];
        const int s0 = (int)(u32)e0;
        const float w0 = __uint_as_float((u32)(e0 >> 32));
        const float4 v0 = *(const float4*)(h + (size_t)s0 * F_H + 4 * f4);
        acc.x += v0.x * w0;
        acc.y += v0.y * w0;
        acc.z += v0.z * w0;
        acc.w += v0.w * w0;
    }
    *(float4*)(agg + (size_t)n * F_H + 4 * f4) = acc;
}

// ---------------------------------------------------------------------------
// GEMM2: h2[N,16] = relu(agg1[N,64]) @ W2[64,16]  (unchanged from R1)
// ---------------------------------------------------------------------------
__global__ __launch_bounds__(256) void gemm2_kernel(
    const float* __restrict__ agg1, const float* __restrict__ W2,
    float* __restrict__ h2, int N) {
    __shared__ float Wlds[64 * 16];
    __shared__ float Xlds[64][65];

    const int tid = threadIdx.x;
    const int n0 = blockIdx.x * 64;

    {
        float4 v = ((const float4*)W2)[tid];
        ((float4*)Wlds)[tid] = v;
    }
    for (int i = tid; i < 64 * 16; i += 256) {
        const int row = i >> 4, c4 = i & 15;
        int n = n0 + row;
        if (n >= N) n = N - 1;
        float4 v = *(const float4*)(agg1 + (size_t)n * F_H + 4 * c4);
        Xlds[row][4 * c4 + 0] = fmaxf(v.x, 0.f);
        Xlds[row][4 * c4 + 1] = fmaxf(v.y, 0.f);
        Xlds[row][4 * c4 + 2] = fmaxf(v.z, 0.f);
        Xlds[row][4 * c4 + 3] = fmaxf(v.w, 0.f);
    }
    __syncthreads();

    const int tf4 = tid & 3;
    const int tn = tid >> 2;
    float a0 = 0.f, a1 = 0.f, a2 = 0.f, a3 = 0.f;
    #pragma unroll 8
    for (int k = 0; k < 64; ++k) {
        const float xv = Xlds[tn][k];
        float4 w4 = *(const float4*)(&Wlds[k * 16 + 4 * tf4]);
        a0 += xv * w4.x;
        a1 += xv * w4.y;
        a2 += xv * w4.z;
        a3 += xv * w4.w;
    }
    const int n = n0 + tn;
    if (n < N) {
        *(float4*)(h2 + (size_t)n * F_OUT + 4 * tf4) = make_float4(a0, a1, a2, a3);
    }
}

// ---------------------------------------------------------------------------
// agg16: out[n] = b2 + sum w_e * h2[src_e]   (F=16, 4 lanes/node)
// ---------------------------------------------------------------------------
__global__ __launch_bounds__(256) void agg16_kernel(
    const float* __restrict__ h, const u64* __restrict__ edata,
    const int* __restrict__ rowptr, const float* __restrict__ bias,
    float* __restrict__ out, int N) {
    const int tid = threadIdx.x;
    const int n = blockIdx.x * 64 + (tid >> 2);
    const int f4 = tid & 3;
    if (n >= N) return;

    float4 acc = *(const float4*)(bias + 4 * f4);
    int i = rowptr[n];
    const int end = rowptr[n + 1];

    for (; i + 1 < end; i += 2) {
        const u64 e0 = edata[i], e1 = edata[i + 1];
        const int s0 = (int)(u32)e0, s1 = (int)(u32)e1;
        const float w0 = __uint_as_float((u32)(e0 >> 32));
        const float w1 = __uint_as_float((u32)(e1 >> 32));
        const float4 v0 = *(const float4*)(h + (size_t)s0 * F_OUT + 4 * f4);
        const float4 v1 = *(const float4*)(h + (size_t)s1 * F_OUT + 4 * f4);
        acc.x += v0.x * w0 + v1.x * w1;
        acc.y += v0.y * w0 + v1.y * w1;
        acc.z += v0.z * w0 + v1.z * w1;
        acc.w += v0.w * w0 + v1.w * w1;
    }
    if (i < end) {
        const u64 e0 = edata[i];
        const int s0 = (int)(u32)e0;
        const float w0 = __uint_as_float((u32)(e0 >> 32));
        const float4 v0 = *(const float4*)(h + (size_t)s0 * F_OUT + 4 * f4);
        acc.x += v0.x * w0;
        acc.y += v0.y * w0;
        acc.z += v0.z * w0;
        acc.w += v0.w * w0;
    }
    *(float4*)(out + (size_t)n * F_OUT + 4 * f4) = acc;
}

extern "C" void kernel_launch(void* const* d_in, const int* in_sizes, int n_in,
                              void* d_out, int out_size, void* d_ws, size_t ws_size,
                              hipStream_t stream) {
    const float* x   = (const float*)d_in[0];
    const int*   src = (const int*)d_in[1];
    const int*   dst = (const int*)d_in[2];
    const float* ew  = (const float*)d_in[3];
    const float* W1  = (const float*)d_in[4];
    const float* b1  = (const float*)d_in[5];
    const float* W2  = (const float*)d_in[6];
    const float* b2  = (const float*)d_in[7];
    float* out = (float*)d_out;

    const int N = in_sizes[0] / F_IN;    // 100000
    const int E = in_sizes[1];           // 1600000

    // workspace layout (bytes, 256-aligned)
    char* base = (char*)d_ws;
    auto align256 = [](size_t v) { return (v + 255) & ~(size_t)255; };
    size_t oH1   = 0;
    size_t oAGG  = align256(oH1  + (size_t)N * F_H * 4);     // 25.6 MB
    size_t oED   = align256(oAGG + (size_t)N * F_H * 4);     // 25.6 MB
    size_t oDEG  = align256(oED  + (size_t)E * 8);           // 12.8 MB
    size_t oROW  = align256(oDEG + (size_t)N * 4);           // 400 KB
    size_t oPART = align256(oROW + (size_t)(N + 1) * 4);     // 400 KB
    // total ~65 MB

    float* h1     = (float*)(base + oH1);
    float* agg1   = (float*)(base + oAGG);
    u64*   edata  = (u64*)(base + oED);
    int*   deg    = (int*)(base + oDEG);   // histogram, then fill cursor
    int*   rowptr = (int*)(base + oROW);
    int*   part   = (int*)(base + oPART);
    float* h2     = h1;                    // reuse h1 region after agg1

    const int NB_E = (E + 255) / 256;          // 6250
    const int NB_N = (N + 255) / 256;          // 391
    const int NB_N1 = (N + 1 + 255) / 256;     // 391

    // ---- build CSR of reverse graph (same every call; rebuilt deterministically)
    hipMemsetAsync(deg, 0, (size_t)N * 4, stream);
    hist_kernel<<<NB_E, 256, 0, stream>>>(dst, deg, E);
    partial_kernel<<<NB_N, 256, 0, stream>>>(deg, part, N);
    scanpart_kernel<<<1, 512, 0, stream>>>(part, NB_N);
    scanfinal_kernel<<<NB_N1, 256, 0, stream>>>(deg, part, rowptr, N, E);
    fill_kernel<<<NB_E, 256, 0, stream>>>(src, dst, ew, deg, edata, E);

    // ---- layer 1
    gemm1_kernel<<<(N + 63) / 64, 256, 0, stream>>>(x, W1, h1, N);
    agg64_kernel<<<(N + 15) / 16, 256, 0, stream>>>(h1, edata, rowptr, b1, agg1, N);

    // ---- layer 2 (relu fused into gemm2 load)
    gemm2_kernel<<<(N + 63) / 64, 256, 0, stream>>>(agg1, W2, h2, N);
    agg16_kernel<<<(N + 63) / 64, 256, 0, stream>>>(h2, edata, rowptr, b2, out, N);
}